// Round 14
// baseline (278.008 us; speedup 1.0000x reference)
//
#include <hip/hip_runtime.h>

typedef short short8 __attribute__((ext_vector_type(8)));
typedef float floatx4 __attribute__((ext_vector_type(4)));
typedef unsigned int u32;

__device__ __forceinline__ float b2f(unsigned short u) {
    union { unsigned int i; float f; } v; v.i = ((unsigned int)u) << 16; return v.f;
}
__device__ __forceinline__ float hi2f(u32 p) {
    union { unsigned int i; float f; } v; v.i = p & 0xFFFF0000u; return v.f;
}
__device__ __forceinline__ float lo2f(u32 p) {
    union { unsigned int i; float f; } v; v.i = p << 16; return v.f;
}
__device__ __forceinline__ unsigned short f2b(float f) {
    union { unsigned int i; float f; } v; v.f = f;
    unsigned int r = v.i + 0x7FFFu + ((v.i >> 16) & 1u);
    return (unsigned short)(r >> 16);
}
// dtype-polymorphic EXTERNAL-input load: f==0 -> bf16, f==1 -> fp32
__device__ __forceinline__ float ld(const void* p, size_t i, int f) {
    return f ? ((const float*)p)[i] : b2f(((const unsigned short*)p)[i]);
}
// inline dtype flag: norm_scale is all-ones; bf16 1.0 = 0x3F80, fp32 low half = 0x0000.
// LOAD-BEARING: dataset is fp32 (rounds 1/9/10 hard-coded bf16 -> NaN).
__device__ __forceinline__ int dtf(const void* scale) {
    return (((const unsigned short*)scale)[0] == 0x3F80u) ? 0 : 1;
}
__device__ __forceinline__ void gload16(const unsigned short* g, unsigned short* l) {
    __builtin_amdgcn_global_load_lds(
        (const __attribute__((address_space(1))) u32*)(const void*)g,
        (__attribute__((address_space(3))) u32*)(void*)l, 16, 0, 0);
}
template<int CTRL>
__device__ __forceinline__ float dpp_add(float y) {
    union { float f; int i; } u, r;
    u.f = y;
    r.i = __builtin_amdgcn_update_dpp(0, u.i, CTRL, 0xF, 0xF, true);
    return y + r.f;
}
#define LOG2E 1.44269504f

// ======== prep: [0,2048) rmsnorm | [2048,3072) w_in^T | [3072,3584) w_out^T ========
__global__ __launch_bounds__(256) void prep_kernel(
    const void* x, const void* scale, unsigned short* __restrict__ h,
    const void* w_in, unsigned short* __restrict__ wT,
    const void* w_out, unsigned short* __restrict__ woT)
{
    const int f = dtf(scale);
    const int b = blockIdx.x, tid = threadIdx.x;
    if (b < 2048) {
        const int t = b;
        float xv[4];
        float ss = 0.f;
        #pragma unroll
        for (int j = 0; j < 4; j++) {
            xv[j] = ld(x, (size_t)t * 1024 + j * 256 + tid, f);
            ss += xv[j] * xv[j];
        }
        #pragma unroll
        for (int o = 32; o > 0; o >>= 1) ss += __shfl_down(ss, o);
        __shared__ float sr[4];
        if ((tid & 63) == 0) sr[tid >> 6] = ss;
        __syncthreads();
        float r = rsqrtf((sr[0] + sr[1] + sr[2] + sr[3]) * (1.f / 1024.f) + 1e-5f);
        #pragma unroll
        for (int j = 0; j < 4; j++) {
            int i = j * 256 + tid;
            h[(size_t)t * 1024 + i] = f2b(xv[j] * r * ld(scale, i, f));
        }
    } else if (b < 3072) {
        __shared__ unsigned short tile[64][68];
        const int idx = b - 2048;
        const int n0 = (idx & 63) * 64, k0 = (idx >> 6) * 64;
        #pragma unroll
        for (int j = 0; j < 16; j++) {
            int ii = tid + 256 * j, r = ii >> 6, c = ii & 63;
            tile[r][c] = f2b(ld(w_in, (size_t)(k0 + r) * 4096 + n0 + c, f));
        }
        __syncthreads();
        #pragma unroll
        for (int j = 0; j < 16; j++) {
            int ii = tid + 256 * j, r = ii >> 6, c = ii & 63;
            wT[(size_t)(n0 + r) * 1024 + k0 + c] = tile[c][r];
        }
    } else {
        __shared__ unsigned short tile[64][68];
        const int idx = b - 3072;
        const int n0 = (idx & 15) * 64, k0 = (idx >> 4) * 64;
        #pragma unroll
        for (int j = 0; j < 16; j++) {
            int ii = tid + 256 * j, r = ii >> 6, c = ii & 63;
            tile[r][c] = f2b(ld(w_out, (size_t)(k0 + r) * 1024 + n0 + c, f));
        }
        __syncthreads();
        #pragma unroll
        for (int j = 0; j < 16; j++) {
            int ii = tid + 256 * j, r = ii >> 6, c = ii & 63;
            woT[(size_t)(n0 + r) * 2048 + k0 + c] = tile[c][r];
        }
    }
}

// ======== MFMA GEMM, TM x 64 tile, BK=64, 4 waves (2x2) ========
template<int KDIM, int NDIM, int TM, int MODE>
__global__ __launch_bounds__(256) void gemm_bt_kernel(
    const unsigned short* __restrict__ A, const unsigned short* __restrict__ BT,
    void* out0, unsigned short* out1, const void* xres, const void* nscale)
{
    constexpr int RT = TM / 32;
    const int f = dtf(nscale);
    __shared__ __align__(16) unsigned short As[TM * 64];
    __shared__ __align__(16) unsigned short Bs[64 * 64];
    const int t = threadIdx.x, w = t >> 6, lane = t & 63;
    const int q = lane >> 4, low = lane & 15;
    const int row0 = blockIdx.y * TM, n0 = blockIdx.x * 64;
    const int wy = w >> 1, wx = w & 1;

    floatx4 acc[RT][2];
    #pragma unroll
    for (int i = 0; i < RT; i++)
        #pragma unroll
        for (int j = 0; j < 2; j++) acc[i][j] = (floatx4){0.f, 0.f, 0.f, 0.f};

    const int srow = lane >> 3, scol = (lane & 7) * 8;
    const unsigned short* a_src = A + (size_t)(row0 + w * (TM / 4) + srow) * KDIM + scol;
    const unsigned short* b_src = BT + (size_t)(n0 + w * 16 + srow) * KDIM + scol;

    for (int k0 = 0; k0 < KDIM; k0 += 64) {
        #pragma unroll
        for (int i = 0; i < TM / 32; i++)
            gload16(a_src + k0 + i * 8 * KDIM, &As[(w * (TM / 4) + i * 8) * 64]);
        #pragma unroll
        for (int i = 0; i < 2; i++)
            gload16(b_src + k0 + i * 8 * KDIM, &Bs[(w * 16 + i * 8) * 64]);
        __syncthreads();
        #pragma unroll
        for (int kh = 0; kh < 2; kh++) {
            short8 af[RT];
            #pragma unroll
            for (int rt = 0; rt < RT; rt++)
                af[rt] = *(const short8*)&As[(wy * (TM / 2) + rt * 16 + low) * 64 + kh * 32 + q * 8];
            #pragma unroll
            for (int nt = 0; nt < 2; nt++) {
                short8 bf = *(const short8*)&Bs[(wx * 32 + nt * 16 + low) * 64 + kh * 32 + q * 8];
                #pragma unroll
                for (int rt = 0; rt < RT; rt++)
                    acc[rt][nt] = __builtin_amdgcn_mfma_f32_16x16x32_bf16(af[rt], bf, acc[rt][nt], 0, 0, 0);
            }
        }
        __syncthreads();
    }

    #pragma unroll
    for (int nt = 0; nt < 2; nt++) {
        const int col = n0 + wx * 32 + nt * 16 + low;
        #pragma unroll
        for (int rt = 0; rt < RT; rt++) {
            #pragma unroll
            for (int r = 0; r < 4; r++) {
                const int row = row0 + wy * (TM / 2) + rt * 16 + q * 4 + r;
                float v = acc[rt][nt][r];
                if (MODE == 0) {
                    if (col < NDIM / 2) {
                        ((unsigned short*)out0)[(size_t)row * (NDIM / 2) + col] = f2b(v);
                    } else {
                        float s = v / (1.f + __expf(-v));
                        out1[(size_t)row * (NDIM / 2) + (col - NDIM / 2)] = f2b(s);
                    }
                } else {
                    size_t idx = (size_t)row * NDIM + col;
                    float o = v + ld(xres, idx, f);
                    if (f) ((float*)out0)[idx] = o;
                    else   ((unsigned short*)out0)[idx] = f2b(o);
                }
            }
        }
    }
}

// -------- causal depthwise conv (K=4) + bias + silu; 8 channels/thread
__global__ __launch_bounds__(256) void conv_kernel(
    const unsigned short* __restrict__ xs_raw, const void* conv_w,
    const void* conv_b, unsigned short* __restrict__ xs_conv, const void* nscale)
{
    const int f = dtf(nscale);
    int id = blockIdx.x * 256 + threadIdx.x;
    int t = id >> 8, c8 = (id & 255) * 8;
    float acc[8];
    if (f) {
        const float* bf = (const float*)conv_b + c8;
        float4 b0 = *(const float4*)bf, b1 = *(const float4*)(bf + 4);
        acc[0] = b0.x; acc[1] = b0.y; acc[2] = b0.z; acc[3] = b0.w;
        acc[4] = b1.x; acc[5] = b1.y; acc[6] = b1.z; acc[7] = b1.w;
    } else {
        uint4 bv = *(const uint4*)((const unsigned short*)conv_b + c8);
        const unsigned short* bp = (const unsigned short*)&bv;
        #pragma unroll
        for (int j = 0; j < 8; j++) acc[j] = b2f(bp[j]);
    }
    #pragma unroll
    for (int k = 0; k < 4; k++) {
        int tt = t - 3 + k;
        if (tt >= 0) {
            uint4 xv = *(const uint4*)(xs_raw + (size_t)tt * 2048 + c8);
            const unsigned short* xp = (const unsigned short*)&xv;
            float wv[8];
            if (f) {
                const float* wf = (const float*)conv_w + (size_t)k * 2048 + c8;
                float4 w0 = *(const float4*)wf, w1 = *(const float4*)(wf + 4);
                wv[0] = w0.x; wv[1] = w0.y; wv[2] = w0.z; wv[3] = w0.w;
                wv[4] = w1.x; wv[5] = w1.y; wv[6] = w1.z; wv[7] = w1.w;
            } else {
                uint4 wu = *(const uint4*)((const unsigned short*)conv_w + (size_t)k * 2048 + c8);
                const unsigned short* wp = (const unsigned short*)&wu;
                #pragma unroll
                for (int j = 0; j < 8; j++) wv[j] = b2f(wp[j]);
            }
            #pragma unroll
            for (int j = 0; j < 8; j++) acc[j] += wv[j] * b2f(xp[j]);
        }
    }
    unsigned short outv[8];
    #pragma unroll
    for (int j = 0; j < 8; j++) {
        float s = acc[j] / (1.f + __expf(-acc[j]));
        outv[j] = f2b(s);
    }
    *(uint4*)(xs_conv + (size_t)t * 2048 + c8) = *(const uint4*)outv;
}

// -------- xproj split-K MFMA, native N=96 (B external, dtype-aware)
__global__ __launch_bounds__(256) void xproj_gemm_kernel(
    const unsigned short* __restrict__ A, const void* B,
    float* __restrict__ partials, const void* nscale)
{
    const int f = dtf(nscale);
    __shared__ __align__(16) unsigned short As[64 * 32];
    __shared__ __align__(16) unsigned short Bs[64 * 32];
    const int t = threadIdx.x;
    const int row0 = blockIdx.y * 64, n0 = blockIdx.x * 64;
    const int ks = blockIdx.z;
    const int wave = t >> 6, lane = t & 63;
    const int q = lane >> 4, low = lane & 15;
    floatx4 acc[4];
    #pragma unroll
    for (int i = 0; i < 4; i++) acc[i] = (floatx4){0.f, 0.f, 0.f, 0.f};
    const int ar = t >> 2, ac = (t & 3) * 8;
    const int bk = t >> 3, bn = (t & 7) * 8;
    const int col0 = n0 + bn;
    const int kbeg = ks * 256, kend = kbeg + 256;
    for (int k0 = kbeg; k0 < kend; k0 += 32) {
        uint4 av = *(const uint4*)(A + (size_t)(row0 + ar) * 2048 + k0 + ac);
        *(uint4*)&As[ar * 32 + ac] = av;
        unsigned short bu[8];
        if (col0 < 96) {
            if (f) {
                const float* Bf = (const float*)B + (size_t)(k0 + bk) * 96 + col0;
                float4 b0 = *(const float4*)Bf, b1 = *(const float4*)(Bf + 4);
                bu[0] = f2b(b0.x); bu[1] = f2b(b0.y); bu[2] = f2b(b0.z); bu[3] = f2b(b0.w);
                bu[4] = f2b(b1.x); bu[5] = f2b(b1.y); bu[6] = f2b(b1.z); bu[7] = f2b(b1.w);
            } else {
                uint4 bv = *(const uint4*)((const unsigned short*)B + (size_t)(k0 + bk) * 96 + col0);
                *(uint4*)bu = bv;
            }
        } else {
            #pragma unroll
            for (int j = 0; j < 8; j++) bu[j] = 0;
        }
        #pragma unroll
        for (int j = 0; j < 8; j++) Bs[(bn + j) * 32 + bk] = bu[j];
        __syncthreads();
        short8 af = *(const short8*)&As[(wave * 16 + low) * 32 + q * 8];
        #pragma unroll
        for (int i = 0; i < 4; i++) {
            short8 bfr = *(const short8*)&Bs[(i * 16 + low) * 32 + q * 8];
            acc[i] = __builtin_amdgcn_mfma_f32_16x16x32_bf16(af, bfr, acc[i], 0, 0, 0);
        }
        __syncthreads();
    }
    float* out = partials + (size_t)ks * (2048 * 128);
    #pragma unroll
    for (int i = 0; i < 4; i++) {
        int col = n0 + i * 16 + low;
        #pragma unroll
        for (int r = 0; r < 4; r++) {
            int row = row0 + wave * 16 + q * 4 + r;
            out[(size_t)row * 128 + col] = acc[i][r];
        }
    }
}

// -------- reduce 8 partials -> proj
__global__ __launch_bounds__(256) void xproj_reduce_kernel(
    const float* __restrict__ partials, float* __restrict__ proj)
{
    int id = blockIdx.x * 256 + threadIdx.x;
    float s = 0.f;
    #pragma unroll
    for (int k = 0; k < 8; k++) s += partials[(size_t)k * (2048 * 128) + id];
    proj[id] = s;
}

// -------- delta MFMA: delta = softplus(proj[:, :64] @ w_dt + b_dt), bf16
__global__ __launch_bounds__(256) void delta_gemm_kernel(
    const float* __restrict__ proj, const void* B, const void* b_dt,
    unsigned short* __restrict__ delta, const void* nscale)
{
    const int f = dtf(nscale);
    __shared__ __align__(16) unsigned short As[64 * 32];
    __shared__ __align__(16) unsigned short Bs[64 * 32];
    const int t = threadIdx.x;
    const int row0 = blockIdx.y * 64, n0 = blockIdx.x * 64;
    const int wave = t >> 6, lane = t & 63;
    const int q = lane >> 4, low = lane & 15;
    floatx4 acc[4];
    #pragma unroll
    for (int i = 0; i < 4; i++) acc[i] = (floatx4){0.f, 0.f, 0.f, 0.f};
    const int ar = t >> 2, ac = (t & 3) * 8;
    const int bk = t >> 3, bn = (t & 7) * 8;
    #pragma unroll
    for (int k0 = 0; k0 < 64; k0 += 32) {
        const float* Ap = proj + (size_t)(row0 + ar) * 128 + k0 + ac;
        float4 a0 = *(const float4*)Ap, a1 = *(const float4*)(Ap + 4);
        As[ar * 32 + ac + 0] = f2b(a0.x); As[ar * 32 + ac + 1] = f2b(a0.y);
        As[ar * 32 + ac + 2] = f2b(a0.z); As[ar * 32 + ac + 3] = f2b(a0.w);
        As[ar * 32 + ac + 4] = f2b(a1.x); As[ar * 32 + ac + 5] = f2b(a1.y);
        As[ar * 32 + ac + 6] = f2b(a1.z); As[ar * 32 + ac + 7] = f2b(a1.w);
        unsigned short bu[8];
        if (f) {
            const float* Bp = (const float*)B + (size_t)(k0 + bk) * 2048 + n0 + bn;
            float4 b0 = *(const float4*)Bp, b1 = *(const float4*)(Bp + 4);
            bu[0] = f2b(b0.x); bu[1] = f2b(b0.y); bu[2] = f2b(b0.z); bu[3] = f2b(b0.w);
            bu[4] = f2b(b1.x); bu[5] = f2b(b1.y); bu[6] = f2b(b1.z); bu[7] = f2b(b1.w);
        } else {
            uint4 bv = *(const uint4*)((const unsigned short*)B + (size_t)(k0 + bk) * 2048 + n0 + bn);
            const unsigned short* bp = (const unsigned short*)&bv;
            #pragma unroll
            for (int j = 0; j < 8; j++) bu[j] = bp[j];
        }
        #pragma unroll
        for (int j = 0; j < 8; j++) Bs[(bn + j) * 32 + bk] = bu[j];
        __syncthreads();
        short8 af = *(const short8*)&As[(wave * 16 + low) * 32 + q * 8];
        #pragma unroll
        for (int i = 0; i < 4; i++) {
            short8 bfr = *(const short8*)&Bs[(i * 16 + low) * 32 + q * 8];
            acc[i] = __builtin_amdgcn_mfma_f32_16x16x32_bf16(af, bfr, acc[i], 0, 0, 0);
        }
        __syncthreads();
    }
    #pragma unroll
    for (int i = 0; i < 4; i++) {
        int col = n0 + i * 16 + low;
        float bias = ld(b_dt, col, f);
        #pragma unroll
        for (int r = 0; r < 4; r++) {
            int row = row0 + wave * 16 + q * 4 + r;
            float v = acc[i][r] + bias;
            float sp = fmaxf(v, 0.f) + log1pf(__expf(-fabsf(v)));
            delta[(size_t)row * 2048 + col] = f2b(sp);
        }
    }
}

// ============ chunked parallel scan: 32 chunks x 64 tokens ============
// Smaller chunks halve LDS (17.5 KB scanC) -> 8 blocks/CU (2x occupancy vs 16x128).
__global__ __launch_bounds__(256) void scanA_kernel(
    const unsigned short* __restrict__ delta, const unsigned short* __restrict__ xs,
    const float* __restrict__ proj, const void* A_log,
    float* __restrict__ Aprod, float* __restrict__ Send, const void* nscale)
{
    const int f = dtf(nscale);
    const int chunk = blockIdx.x, c0 = blockIdx.y * 16, t0 = chunk * 64;
    __shared__ __align__(16) u32 dxl[16 * 68];
    __shared__ __align__(16) float Bt[16 * 68];
    const int tid = threadIdx.x;
    #pragma unroll
    for (int j = 0; j < 2; j++) {
        int idx = tid + 256 * j;                 // 512 = 64 t x 8 cpairs
        int t = idx >> 3, cp = (idx & 7) * 2;
        u32 dpair = *(const u32*)(delta + (size_t)(t0 + t) * 2048 + c0 + cp);
        u32 xpair = *(const u32*)(xs    + (size_t)(t0 + t) * 2048 + c0 + cp);
        dxl[cp * 68 + t]       = (dpair << 16) | (xpair & 0xFFFFu);
        dxl[(cp + 1) * 68 + t] = (dpair & 0xFFFF0000u) | (xpair >> 16);
    }
    #pragma unroll
    for (int j = 0; j < 4; j++) {
        int idx = tid + 256 * j;                 // 1024 = 64 t x 16 n
        int t = idx >> 4, n = idx & 15;
        Bt[n * 68 + t] = proj[(size_t)(t0 + t) * 128 + 64 + n];
    }
    __syncthreads();
    const int cl = tid >> 4, n = tid & 15;
    const float A2 = -__expf(ld(A_log, (size_t)(c0 + cl) * 16 + n, f)) * LOG2E;
    float s = 0.f, dsum = 0.f;
    for (int t4 = 0; t4 < 64; t4 += 4) {
        uint4  dx4 = *(const uint4*)&dxl[cl * 68 + t4];
        float4 b4  = *(const float4*)&Bt[n * 68 + t4];
        const u32* dxp = (const u32*)&dx4;
        const float* bp = (const float*)&b4;
        #pragma unroll
        for (int j = 0; j < 4; j++) {
            u32 p = dxp[j];
            float dv = hi2f(p), xv = lo2f(p);
            float a = exp2f(dv * A2);
            s = a * s + dv * xv * bp[j];
            dsum += dv;
        }
    }
    size_t o = (size_t)chunk * 32768 + (size_t)c0 * 16 + tid;
    Aprod[o] = exp2f(A2 * dsum);
    Send[o]  = s;
}

// scanC: inline chunk-prefix, replay, DPP y-reduce, vector epilogue. inner aliases res.
__global__ __launch_bounds__(256) void scanC_kernel(
    const unsigned short* __restrict__ delta, const unsigned short* __restrict__ xs,
    const float* __restrict__ proj, const void* A_log, const void* Dv,
    const float* __restrict__ Aprod, const float* __restrict__ Send,
    const unsigned short* __restrict__ res, unsigned short* __restrict__ inner,
    const void* nscale)
{
    const int f = dtf(nscale);
    const int chunk = blockIdx.x, c0 = blockIdx.y * 16, t0 = chunk * 64;
    __shared__ __align__(16) u32 dxl[16 * 68];
    __shared__ __align__(16) float Bt[16 * 68];
    __shared__ __align__(16) float Ct[16 * 68];
    __shared__ __align__(16) float yl[16 * 68];
    __shared__ float Dl[16];
    const int tid = threadIdx.x;
    if (tid < 16) Dl[tid] = ld(Dv, c0 + tid, f);
    // inline prefix over earlier chunks
    const int g = c0 * 16 + tid;
    float s = 0.f;
    for (int k = 0; k < chunk; k++)
        s = Aprod[(size_t)k * 32768 + g] * s + Send[(size_t)k * 32768 + g];
    #pragma unroll
    for (int j = 0; j < 2; j++) {
        int idx = tid + 256 * j;
        int t = idx >> 3, cp = (idx & 7) * 2;
        u32 dpair = *(const u32*)(delta + (size_t)(t0 + t) * 2048 + c0 + cp);
        u32 xpair = *(const u32*)(xs    + (size_t)(t0 + t) * 2048 + c0 + cp);
        dxl[cp * 68 + t]       = (dpair << 16) | (xpair & 0xFFFFu);
        dxl[(cp + 1) * 68 + t] = (dpair & 0xFFFF0000u) | (xpair >> 16);
    }
    #pragma unroll
    for (int j = 0; j < 4; j++) {
        int idx = tid + 256 * j;
        int t = idx >> 4, n = idx & 15;
        Bt[n * 68 + t] = proj[(size_t)(t0 + t) * 128 + 64 + n];
        Ct[n * 68 + t] = proj[(size_t)(t0 + t) * 128 + 80 + n];
    }
    __syncthreads();
    const int cl = tid >> 4, n = tid & 15;
    const float A2 = -__expf(ld(A_log, (size_t)(c0 + cl) * 16 + n, f)) * LOG2E;
    for (int t4 = 0; t4 < 64; t4 += 4) {
        uint4  dx4 = *(const uint4*)&dxl[cl * 68 + t4];
        float4 b4  = *(const float4*)&Bt[n * 68 + t4];
        float4 c4  = *(const float4*)&Ct[n * 68 + t4];
        const u32* dxp = (const u32*)&dx4;
        const float* bp = (const float*)&b4;
        const float* cp = (const float*)&c4;
        #pragma unroll
        for (int j = 0; j < 4; j++) {
            u32 p = dxp[j];
            float dv = hi2f(p), xv = lo2f(p);
            float a = exp2f(dv * A2);
            s = a * s + dv * xv * bp[j];
            float y = s * cp[j];
            y = dpp_add<0x111>(y);
            y = dpp_add<0x112>(y);
            y = dpp_add<0x114>(y);
            y = dpp_add<0x118>(y);
            if (n == 15) yl[cl * 68 + t4 + j] = y;
        }
    }
    __syncthreads();
    // epilogue: thread -> (t = tid>>2, 4 channels); uint2 res read / inner write
    const int et = tid >> 2, ech = (tid & 3) * 4;
    size_t gbase = (size_t)(t0 + et) * 2048 + c0 + ech;
    uint2 rv2 = *(const uint2*)(res + gbase);
    const unsigned short* rp = (const unsigned short*)&rv2;
    unsigned short outv[4];
    #pragma unroll
    for (int j = 0; j < 4; j++) {
        int c = ech + j;
        float y  = yl[c * 68 + et];
        float xv = lo2f(dxl[c * 68 + et]);
        float o  = (y + xv * Dl[c]) * b2f(rp[j]);
        outv[j] = f2b(o);
    }
    *(uint2*)(inner + gbase) = *(const uint2*)outv;
}

extern "C" void kernel_launch(void* const* d_in, const int* in_sizes, int n_in,
                              void* d_out, int out_size, void* d_ws, size_t ws_size,
                              hipStream_t stream) {
    const void* x       = d_in[0];
    const void* nscale  = d_in[1];
    const void* w_in    = d_in[2];
    const void* conv_w  = d_in[3];
    const void* conv_b  = d_in[4];
    const void* A_log   = d_in[5];
    const void* Dv      = d_in[6];
    const void* w_xproj = d_in[7];
    const void* w_dt    = d_in[8];
    const void* b_dt    = d_in[9];
    const void* w_out   = d_in[10];

    // disjoint workspace layout (~65 MB of the ~260 MB ws)
    char* ws = (char*)d_ws;
    const size_t MB = 1048576;
    unsigned short* xs_raw  = (unsigned short*)(ws);            // 8 MB
    unsigned short* res_s   = (unsigned short*)(ws + 8 * MB);   // 8 MB (inner in-place)
    unsigned short* xs_conv = (unsigned short*)(ws + 16 * MB);  // 8 MB
    unsigned short* delta   = (unsigned short*)(ws + 24 * MB);  // 8 MB
    unsigned short* h_norm  = (unsigned short*)(ws + 32 * MB);  // 4 MB
    unsigned short* wT      = (unsigned short*)(ws + 36 * MB);  // 8 MB
    unsigned short* woT     = (unsigned short*)(ws + 44 * MB);  // 4 MB
    float*          partials= (float*)(ws + 48 * MB);           // 8 MB
    float*          proj    = (float*)(ws + 56 * MB);           // 1 MB
    float*          Aprod   = (float*)(ws + 57 * MB);           // 4 MB (32 chunks)
    float*          Send    = (float*)(ws + 61 * MB);           // 4 MB
    unsigned short* inner   = res_s;                            // in-place (same-thread RAW)

    prep_kernel<<<3584, 256, 0, stream>>>(x, nscale, h_norm, w_in, wT, w_out, woT);
    gemm_bt_kernel<1024, 4096, 128, 0><<<dim3(64, 16), 256, 0, stream>>>(
        h_norm, wT, xs_raw, res_s, nullptr, nscale);
    conv_kernel<<<2048, 256, 0, stream>>>(xs_raw, conv_w, conv_b, xs_conv, nscale);
    xproj_gemm_kernel<<<dim3(2, 32, 8), 256, 0, stream>>>(xs_conv, w_xproj, partials, nscale);
    xproj_reduce_kernel<<<1024, 256, 0, stream>>>(partials, proj);
    delta_gemm_kernel<<<dim3(32, 32), 256, 0, stream>>>(proj, w_dt, b_dt, delta, nscale);
    scanA_kernel<<<dim3(32, 128), 256, 0, stream>>>(delta, xs_conv, proj, A_log, Aprod, Send, nscale);
    scanC_kernel<<<dim3(32, 128), 256, 0, stream>>>(delta, xs_conv, proj, A_log, Dv, Aprod, Send, res_s, inner, nscale);
    gemm_bt_kernel<2048, 1024, 64, 1><<<dim3(16, 32), 256, 0, stream>>>(
        inner, woT, d_out, nullptr, x, nscale);
}

// Round 15
// 273.351 us; speedup vs baseline: 1.0170x; 1.0170x over previous
//
#include <hip/hip_runtime.h>

typedef short short8 __attribute__((ext_vector_type(8)));
typedef float floatx4 __attribute__((ext_vector_type(4)));
typedef unsigned int u32;

__device__ __forceinline__ float b2f(unsigned short u) {
    union { unsigned int i; float f; } v; v.i = ((unsigned int)u) << 16; return v.f;
}
__device__ __forceinline__ float hi2f(u32 p) {
    union { unsigned int i; float f; } v; v.i = p & 0xFFFF0000u; return v.f;
}
__device__ __forceinline__ float lo2f(u32 p) {
    union { unsigned int i; float f; } v; v.i = p << 16; return v.f;
}
__device__ __forceinline__ unsigned short f2b(float f) {
    union { unsigned int i; float f; } v; v.f = f;
    unsigned int r = v.i + 0x7FFFu + ((v.i >> 16) & 1u);
    return (unsigned short)(r >> 16);
}
// dtype-polymorphic EXTERNAL-input load: f==0 -> bf16, f==1 -> fp32
__device__ __forceinline__ float ld(const void* p, size_t i, int f) {
    return f ? ((const float*)p)[i] : b2f(((const unsigned short*)p)[i]);
}
// inline dtype flag: norm_scale is all-ones; bf16 1.0 = 0x3F80, fp32 low half = 0x0000.
// LOAD-BEARING: dataset is fp32 (rounds 1/9/10 hard-coded bf16 -> NaN).
__device__ __forceinline__ int dtf(const void* scale) {
    return (((const unsigned short*)scale)[0] == 0x3F80u) ? 0 : 1;
}
__device__ __forceinline__ void gload16(const unsigned short* g, unsigned short* l) {
    __builtin_amdgcn_global_load_lds(
        (const __attribute__((address_space(1))) u32*)(const void*)g,
        (__attribute__((address_space(3))) u32*)(void*)l, 16, 0, 0);
}
template<int CTRL>
__device__ __forceinline__ float dpp_add(float y) {
    union { float f; int i; } u, r;
    u.f = y;
    r.i = __builtin_amdgcn_update_dpp(0, u.i, CTRL, 0xF, 0xF, true);
    return y + r.f;
}
#define LOG2E 1.44269504f

// ======== prep: [0,2048) rmsnorm | [2048,3072) w_in^T | [3072,3584) w_out^T ========
__global__ __launch_bounds__(256) void prep_kernel(
    const void* x, const void* scale, unsigned short* __restrict__ h,
    const void* w_in, unsigned short* __restrict__ wT,
    const void* w_out, unsigned short* __restrict__ woT)
{
    const int f = dtf(scale);
    const int b = blockIdx.x, tid = threadIdx.x;
    if (b < 2048) {
        const int t = b;
        float xv[4];
        float ss = 0.f;
        #pragma unroll
        for (int j = 0; j < 4; j++) {
            xv[j] = ld(x, (size_t)t * 1024 + j * 256 + tid, f);
            ss += xv[j] * xv[j];
        }
        #pragma unroll
        for (int o = 32; o > 0; o >>= 1) ss += __shfl_down(ss, o);
        __shared__ float sr[4];
        if ((tid & 63) == 0) sr[tid >> 6] = ss;
        __syncthreads();
        float r = rsqrtf((sr[0] + sr[1] + sr[2] + sr[3]) * (1.f / 1024.f) + 1e-5f);
        #pragma unroll
        for (int j = 0; j < 4; j++) {
            int i = j * 256 + tid;
            h[(size_t)t * 1024 + i] = f2b(xv[j] * r * ld(scale, i, f));
        }
    } else if (b < 3072) {
        __shared__ unsigned short tile[64][68];
        const int idx = b - 2048;
        const int n0 = (idx & 63) * 64, k0 = (idx >> 6) * 64;
        #pragma unroll
        for (int j = 0; j < 16; j++) {
            int ii = tid + 256 * j, r = ii >> 6, c = ii & 63;
            tile[r][c] = f2b(ld(w_in, (size_t)(k0 + r) * 4096 + n0 + c, f));
        }
        __syncthreads();
        #pragma unroll
        for (int j = 0; j < 16; j++) {
            int ii = tid + 256 * j, r = ii >> 6, c = ii & 63;
            wT[(size_t)(n0 + r) * 1024 + k0 + c] = tile[c][r];
        }
    } else {
        __shared__ unsigned short tile[64][68];
        const int idx = b - 3072;
        const int n0 = (idx & 15) * 64, k0 = (idx >> 4) * 64;
        #pragma unroll
        for (int j = 0; j < 16; j++) {
            int ii = tid + 256 * j, r = ii >> 6, c = ii & 63;
            tile[r][c] = f2b(ld(w_out, (size_t)(k0 + r) * 1024 + n0 + c, f));
        }
        __syncthreads();
        #pragma unroll
        for (int j = 0; j < 16; j++) {
            int ii = tid + 256 * j, r = ii >> 6, c = ii & 63;
            woT[(size_t)(n0 + r) * 2048 + k0 + c] = tile[c][r];
        }
    }
}

// ======== MFMA GEMM, TM x 64 tile, BK=64, 4 waves (2x2) ========
template<int KDIM, int NDIM, int TM, int MODE>
__global__ __launch_bounds__(256) void gemm_bt_kernel(
    const unsigned short* __restrict__ A, const unsigned short* __restrict__ BT,
    void* out0, unsigned short* out1, const void* xres, const void* nscale)
{
    constexpr int RT = TM / 32;
    const int f = dtf(nscale);
    __shared__ __align__(16) unsigned short As[TM * 64];
    __shared__ __align__(16) unsigned short Bs[64 * 64];
    const int t = threadIdx.x, w = t >> 6, lane = t & 63;
    const int q = lane >> 4, low = lane & 15;
    const int row0 = blockIdx.y * TM, n0 = blockIdx.x * 64;
    const int wy = w >> 1, wx = w & 1;

    floatx4 acc[RT][2];
    #pragma unroll
    for (int i = 0; i < RT; i++)
        #pragma unroll
        for (int j = 0; j < 2; j++) acc[i][j] = (floatx4){0.f, 0.f, 0.f, 0.f};

    const int srow = lane >> 3, scol = (lane & 7) * 8;
    const unsigned short* a_src = A + (size_t)(row0 + w * (TM / 4) + srow) * KDIM + scol;
    const unsigned short* b_src = BT + (size_t)(n0 + w * 16 + srow) * KDIM + scol;

    for (int k0 = 0; k0 < KDIM; k0 += 64) {
        #pragma unroll
        for (int i = 0; i < TM / 32; i++)
            gload16(a_src + k0 + i * 8 * KDIM, &As[(w * (TM / 4) + i * 8) * 64]);
        #pragma unroll
        for (int i = 0; i < 2; i++)
            gload16(b_src + k0 + i * 8 * KDIM, &Bs[(w * 16 + i * 8) * 64]);
        __syncthreads();
        #pragma unroll
        for (int kh = 0; kh < 2; kh++) {
            short8 af[RT];
            #pragma unroll
            for (int rt = 0; rt < RT; rt++)
                af[rt] = *(const short8*)&As[(wy * (TM / 2) + rt * 16 + low) * 64 + kh * 32 + q * 8];
            #pragma unroll
            for (int nt = 0; nt < 2; nt++) {
                short8 bf = *(const short8*)&Bs[(wx * 32 + nt * 16 + low) * 64 + kh * 32 + q * 8];
                #pragma unroll
                for (int rt = 0; rt < RT; rt++)
                    acc[rt][nt] = __builtin_amdgcn_mfma_f32_16x16x32_bf16(af[rt], bf, acc[rt][nt], 0, 0, 0);
            }
        }
        __syncthreads();
    }

    #pragma unroll
    for (int nt = 0; nt < 2; nt++) {
        const int col = n0 + wx * 32 + nt * 16 + low;
        #pragma unroll
        for (int rt = 0; rt < RT; rt++) {
            #pragma unroll
            for (int r = 0; r < 4; r++) {
                const int row = row0 + wy * (TM / 2) + rt * 16 + q * 4 + r;
                float v = acc[rt][nt][r];
                if (MODE == 0) {
                    if (col < NDIM / 2) {
                        ((unsigned short*)out0)[(size_t)row * (NDIM / 2) + col] = f2b(v);
                    } else {
                        float s = v / (1.f + __expf(-v));
                        out1[(size_t)row * (NDIM / 2) + (col - NDIM / 2)] = f2b(s);
                    }
                } else {
                    size_t idx = (size_t)row * NDIM + col;
                    float o = v + ld(xres, idx, f);
                    if (f) ((float*)out0)[idx] = o;
                    else   ((unsigned short*)out0)[idx] = f2b(o);
                }
            }
        }
    }
}

// -------- causal depthwise conv (K=4) + bias + silu; 8 channels/thread
__global__ __launch_bounds__(256) void conv_kernel(
    const unsigned short* __restrict__ xs_raw, const void* conv_w,
    const void* conv_b, unsigned short* __restrict__ xs_conv, const void* nscale)
{
    const int f = dtf(nscale);
    int id = blockIdx.x * 256 + threadIdx.x;
    int t = id >> 8, c8 = (id & 255) * 8;
    float acc[8];
    if (f) {
        const float* bf = (const float*)conv_b + c8;
        float4 b0 = *(const float4*)bf, b1 = *(const float4*)(bf + 4);
        acc[0] = b0.x; acc[1] = b0.y; acc[2] = b0.z; acc[3] = b0.w;
        acc[4] = b1.x; acc[5] = b1.y; acc[6] = b1.z; acc[7] = b1.w;
    } else {
        uint4 bv = *(const uint4*)((const unsigned short*)conv_b + c8);
        const unsigned short* bp = (const unsigned short*)&bv;
        #pragma unroll
        for (int j = 0; j < 8; j++) acc[j] = b2f(bp[j]);
    }
    #pragma unroll
    for (int k = 0; k < 4; k++) {
        int tt = t - 3 + k;
        if (tt >= 0) {
            uint4 xv = *(const uint4*)(xs_raw + (size_t)tt * 2048 + c8);
            const unsigned short* xp = (const unsigned short*)&xv;
            float wv[8];
            if (f) {
                const float* wf = (const float*)conv_w + (size_t)k * 2048 + c8;
                float4 w0 = *(const float4*)wf, w1 = *(const float4*)(wf + 4);
                wv[0] = w0.x; wv[1] = w0.y; wv[2] = w0.z; wv[3] = w0.w;
                wv[4] = w1.x; wv[5] = w1.y; wv[6] = w1.z; wv[7] = w1.w;
            } else {
                uint4 wu = *(const uint4*)((const unsigned short*)conv_w + (size_t)k * 2048 + c8);
                const unsigned short* wp = (const unsigned short*)&wu;
                #pragma unroll
                for (int j = 0; j < 8; j++) wv[j] = b2f(wp[j]);
            }
            #pragma unroll
            for (int j = 0; j < 8; j++) acc[j] += wv[j] * b2f(xp[j]);
        }
    }
    unsigned short outv[8];
    #pragma unroll
    for (int j = 0; j < 8; j++) {
        float s = acc[j] / (1.f + __expf(-acc[j]));
        outv[j] = f2b(s);
    }
    *(uint4*)(xs_conv + (size_t)t * 2048 + c8) = *(const uint4*)outv;
}

// -------- xproj split-K MFMA, native N=96 (B external, dtype-aware)
__global__ __launch_bounds__(256) void xproj_gemm_kernel(
    const unsigned short* __restrict__ A, const void* B,
    float* __restrict__ partials, const void* nscale)
{
    const int f = dtf(nscale);
    __shared__ __align__(16) unsigned short As[64 * 32];
    __shared__ __align__(16) unsigned short Bs[64 * 32];
    const int t = threadIdx.x;
    const int row0 = blockIdx.y * 64, n0 = blockIdx.x * 64;
    const int ks = blockIdx.z;
    const int wave = t >> 6, lane = t & 63;
    const int q = lane >> 4, low = lane & 15;
    floatx4 acc[4];
    #pragma unroll
    for (int i = 0; i < 4; i++) acc[i] = (floatx4){0.f, 0.f, 0.f, 0.f};
    const int ar = t >> 2, ac = (t & 3) * 8;
    const int bk = t >> 3, bn = (t & 7) * 8;
    const int col0 = n0 + bn;
    const int kbeg = ks * 256, kend = kbeg + 256;
    for (int k0 = kbeg; k0 < kend; k0 += 32) {
        uint4 av = *(const uint4*)(A + (size_t)(row0 + ar) * 2048 + k0 + ac);
        *(uint4*)&As[ar * 32 + ac] = av;
        unsigned short bu[8];
        if (col0 < 96) {
            if (f) {
                const float* Bf = (const float*)B + (size_t)(k0 + bk) * 96 + col0;
                float4 b0 = *(const float4*)Bf, b1 = *(const float4*)(Bf + 4);
                bu[0] = f2b(b0.x); bu[1] = f2b(b0.y); bu[2] = f2b(b0.z); bu[3] = f2b(b0.w);
                bu[4] = f2b(b1.x); bu[5] = f2b(b1.y); bu[6] = f2b(b1.z); bu[7] = f2b(b1.w);
            } else {
                uint4 bv = *(const uint4*)((const unsigned short*)B + (size_t)(k0 + bk) * 96 + col0);
                *(uint4*)bu = bv;
            }
        } else {
            #pragma unroll
            for (int j = 0; j < 8; j++) bu[j] = 0;
        }
        #pragma unroll
        for (int j = 0; j < 8; j++) Bs[(bn + j) * 32 + bk] = bu[j];
        __syncthreads();
        short8 af = *(const short8*)&As[(wave * 16 + low) * 32 + q * 8];
        #pragma unroll
        for (int i = 0; i < 4; i++) {
            short8 bfr = *(const short8*)&Bs[(i * 16 + low) * 32 + q * 8];
            acc[i] = __builtin_amdgcn_mfma_f32_16x16x32_bf16(af, bfr, acc[i], 0, 0, 0);
        }
        __syncthreads();
    }
    float* out = partials + (size_t)ks * (2048 * 128);
    #pragma unroll
    for (int i = 0; i < 4; i++) {
        int col = n0 + i * 16 + low;
        #pragma unroll
        for (int r = 0; r < 4; r++) {
            int row = row0 + wave * 16 + q * 4 + r;
            out[(size_t)row * 128 + col] = acc[i][r];
        }
    }
}

// -------- reduce 8 partials -> proj
__global__ __launch_bounds__(256) void xproj_reduce_kernel(
    const float* __restrict__ partials, float* __restrict__ proj)
{
    int id = blockIdx.x * 256 + threadIdx.x;
    float s = 0.f;
    #pragma unroll
    for (int k = 0; k < 8; k++) s += partials[(size_t)k * (2048 * 128) + id];
    proj[id] = s;
}

// -------- delta MFMA: delta = softplus(proj[:, :64] @ w_dt + b_dt), bf16
__global__ __launch_bounds__(256) void delta_gemm_kernel(
    const float* __restrict__ proj, const void* B, const void* b_dt,
    unsigned short* __restrict__ delta, const void* nscale)
{
    const int f = dtf(nscale);
    __shared__ __align__(16) unsigned short As[64 * 32];
    __shared__ __align__(16) unsigned short Bs[64 * 32];
    const int t = threadIdx.x;
    const int row0 = blockIdx.y * 64, n0 = blockIdx.x * 64;
    const int wave = t >> 6, lane = t & 63;
    const int q = lane >> 4, low = lane & 15;
    floatx4 acc[4];
    #pragma unroll
    for (int i = 0; i < 4; i++) acc[i] = (floatx4){0.f, 0.f, 0.f, 0.f};
    const int ar = t >> 2, ac = (t & 3) * 8;
    const int bk = t >> 3, bn = (t & 7) * 8;
    #pragma unroll
    for (int k0 = 0; k0 < 64; k0 += 32) {
        const float* Ap = proj + (size_t)(row0 + ar) * 128 + k0 + ac;
        float4 a0 = *(const float4*)Ap, a1 = *(const float4*)(Ap + 4);
        As[ar * 32 + ac + 0] = f2b(a0.x); As[ar * 32 + ac + 1] = f2b(a0.y);
        As[ar * 32 + ac + 2] = f2b(a0.z); As[ar * 32 + ac + 3] = f2b(a0.w);
        As[ar * 32 + ac + 4] = f2b(a1.x); As[ar * 32 + ac + 5] = f2b(a1.y);
        As[ar * 32 + ac + 6] = f2b(a1.z); As[ar * 32 + ac + 7] = f2b(a1.w);
        unsigned short bu[8];
        if (f) {
            const float* Bp = (const float*)B + (size_t)(k0 + bk) * 2048 + n0 + bn;
            float4 b0 = *(const float4*)Bp, b1 = *(const float4*)(Bp + 4);
            bu[0] = f2b(b0.x); bu[1] = f2b(b0.y); bu[2] = f2b(b0.z); bu[3] = f2b(b0.w);
            bu[4] = f2b(b1.x); bu[5] = f2b(b1.y); bu[6] = f2b(b1.z); bu[7] = f2b(b1.w);
        } else {
            uint4 bv = *(const uint4*)((const unsigned short*)B + (size_t)(k0 + bk) * 2048 + n0 + bn);
            const unsigned short* bp = (const unsigned short*)&bv;
            #pragma unroll
            for (int j = 0; j < 8; j++) bu[j] = bp[j];
        }
        #pragma unroll
        for (int j = 0; j < 8; j++) Bs[(bn + j) * 32 + bk] = bu[j];
        __syncthreads();
        short8 af = *(const short8*)&As[(wave * 16 + low) * 32 + q * 8];
        #pragma unroll
        for (int i = 0; i < 4; i++) {
            short8 bfr = *(const short8*)&Bs[(i * 16 + low) * 32 + q * 8];
            acc[i] = __builtin_amdgcn_mfma_f32_16x16x32_bf16(af, bfr, acc[i], 0, 0, 0);
        }
        __syncthreads();
    }
    #pragma unroll
    for (int i = 0; i < 4; i++) {
        int col = n0 + i * 16 + low;
        float bias = ld(b_dt, col, f);
        #pragma unroll
        for (int r = 0; r < 4; r++) {
            int row = row0 + wave * 16 + q * 4 + r;
            float v = acc[i][r] + bias;
            float sp = fmaxf(v, 0.f) + log1pf(__expf(-fabsf(v)));
            delta[(size_t)row * 2048 + col] = f2b(sp);
        }
    }
}

// ============ chunked parallel scan: 32 chunks x 64 tokens ============
__global__ __launch_bounds__(256) void scanA_kernel(
    const unsigned short* __restrict__ delta, const unsigned short* __restrict__ xs,
    const float* __restrict__ proj, const void* A_log,
    float* __restrict__ Aprod, float* __restrict__ Send, const void* nscale)
{
    const int f = dtf(nscale);
    const int chunk = blockIdx.x, c0 = blockIdx.y * 16, t0 = chunk * 64;
    __shared__ __align__(16) u32 dxl[16 * 68];
    __shared__ __align__(16) float Bt[16 * 68];
    const int tid = threadIdx.x;
    #pragma unroll
    for (int j = 0; j < 2; j++) {
        int idx = tid + 256 * j;
        int t = idx >> 3, cp = (idx & 7) * 2;
        u32 dpair = *(const u32*)(delta + (size_t)(t0 + t) * 2048 + c0 + cp);
        u32 xpair = *(const u32*)(xs    + (size_t)(t0 + t) * 2048 + c0 + cp);
        dxl[cp * 68 + t]       = (dpair << 16) | (xpair & 0xFFFFu);
        dxl[(cp + 1) * 68 + t] = (dpair & 0xFFFF0000u) | (xpair >> 16);
    }
    #pragma unroll
    for (int j = 0; j < 4; j++) {
        int idx = tid + 256 * j;
        int t = idx >> 4, n = idx & 15;
        Bt[n * 68 + t] = proj[(size_t)(t0 + t) * 128 + 64 + n];
    }
    __syncthreads();
    const int cl = tid >> 4, n = tid & 15;
    const float A2 = -__expf(ld(A_log, (size_t)(c0 + cl) * 16 + n, f)) * LOG2E;
    float s = 0.f, dsum = 0.f;
    for (int t4 = 0; t4 < 64; t4 += 4) {
        uint4  dx4 = *(const uint4*)&dxl[cl * 68 + t4];
        float4 b4  = *(const float4*)&Bt[n * 68 + t4];
        const u32* dxp = (const u32*)&dx4;
        const float* bp = (const float*)&b4;
        #pragma unroll
        for (int j = 0; j < 4; j++) {
            u32 p = dxp[j];
            float dv = hi2f(p), xv = lo2f(p);
            float a = exp2f(dv * A2);
            s = a * s + dv * xv * bp[j];
            dsum += dv;
        }
    }
    size_t o = (size_t)chunk * 32768 + (size_t)c0 * 16 + tid;
    Aprod[o] = exp2f(A2 * dsum);
    Send[o]  = s;
}

// scanB: prefix over 32 chunk aggregates (compile-time-unrolled register pipeline)
__global__ __launch_bounds__(256) void scanB_kernel(
    const float* __restrict__ Aprod, const float* __restrict__ Send,
    float* __restrict__ prefix)
{
    int g = blockIdx.x * 256 + threadIdx.x;
    float a[32], b[32];
    #pragma unroll
    for (int k = 0; k < 32; k++) { a[k] = Aprod[(size_t)k * 32768 + g]; b[k] = Send[(size_t)k * 32768 + g]; }
    float s = 0.f;
    #pragma unroll
    for (int k = 0; k < 32; k++) { prefix[(size_t)k * 32768 + g] = s; s = a[k] * s + b[k]; }
}

// scanC: prefix load, replay, DPP y-reduce, vector epilogue. inner aliases res.
__global__ __launch_bounds__(256) void scanC_kernel(
    const unsigned short* __restrict__ delta, const unsigned short* __restrict__ xs,
    const float* __restrict__ proj, const void* A_log, const void* Dv,
    const float* __restrict__ prefix,
    const unsigned short* __restrict__ res, unsigned short* __restrict__ inner,
    const void* nscale)
{
    const int f = dtf(nscale);
    const int chunk = blockIdx.x, c0 = blockIdx.y * 16, t0 = chunk * 64;
    __shared__ __align__(16) u32 dxl[16 * 68];
    __shared__ __align__(16) float Bt[16 * 68];
    __shared__ __align__(16) float Ct[16 * 68];
    __shared__ __align__(16) float yl[16 * 68];
    __shared__ float Dl[16];
    const int tid = threadIdx.x;
    if (tid < 16) Dl[tid] = ld(Dv, c0 + tid, f);
    float s = prefix[(size_t)chunk * 32768 + (size_t)c0 * 16 + tid];
    #pragma unroll
    for (int j = 0; j < 2; j++) {
        int idx = tid + 256 * j;
        int t = idx >> 3, cp = (idx & 7) * 2;
        u32 dpair = *(const u32*)(delta + (size_t)(t0 + t) * 2048 + c0 + cp);
        u32 xpair = *(const u32*)(xs    + (size_t)(t0 + t) * 2048 + c0 + cp);
        dxl[cp * 68 + t]       = (dpair << 16) | (xpair & 0xFFFFu);
        dxl[(cp + 1) * 68 + t] = (dpair & 0xFFFF0000u) | (xpair >> 16);
    }
    #pragma unroll
    for (int j = 0; j < 4; j++) {
        int idx = tid + 256 * j;
        int t = idx >> 4, n = idx & 15;
        Bt[n * 68 + t] = proj[(size_t)(t0 + t) * 128 + 64 + n];
        Ct[n * 68 + t] = proj[(size_t)(t0 + t) * 128 + 80 + n];
    }
    __syncthreads();
    const int cl = tid >> 4, n = tid & 15;
    const float A2 = -__expf(ld(A_log, (size_t)(c0 + cl) * 16 + n, f)) * LOG2E;
    for (int t4 = 0; t4 < 64; t4 += 4) {
        uint4  dx4 = *(const uint4*)&dxl[cl * 68 + t4];
        float4 b4  = *(const float4*)&Bt[n * 68 + t4];
        float4 c4  = *(const float4*)&Ct[n * 68 + t4];
        const u32* dxp = (const u32*)&dx4;
        const float* bp = (const float*)&b4;
        const float* cp = (const float*)&c4;
        #pragma unroll
        for (int j = 0; j < 4; j++) {
            u32 p = dxp[j];
            float dv = hi2f(p), xv = lo2f(p);
            float a = exp2f(dv * A2);
            s = a * s + dv * xv * bp[j];
            float y = s * cp[j];
            y = dpp_add<0x111>(y);
            y = dpp_add<0x112>(y);
            y = dpp_add<0x114>(y);
            y = dpp_add<0x118>(y);
            if (n == 15) yl[cl * 68 + t4 + j] = y;
        }
    }
    __syncthreads();
    const int et = tid >> 2, ech = (tid & 3) * 4;
    size_t gbase = (size_t)(t0 + et) * 2048 + c0 + ech;
    uint2 rv2 = *(const uint2*)(res + gbase);
    const unsigned short* rp = (const unsigned short*)&rv2;
    unsigned short outv[4];
    #pragma unroll
    for (int j = 0; j < 4; j++) {
        int c = ech + j;
        float y  = yl[c * 68 + et];
        float xv = lo2f(dxl[c * 68 + et]);
        float o  = (y + xv * Dl[c]) * b2f(rp[j]);
        outv[j] = f2b(o);
    }
    *(uint2*)(inner + gbase) = *(const uint2*)outv;
}

extern "C" void kernel_launch(void* const* d_in, const int* in_sizes, int n_in,
                              void* d_out, int out_size, void* d_ws, size_t ws_size,
                              hipStream_t stream) {
    const void* x       = d_in[0];
    const void* nscale  = d_in[1];
    const void* w_in    = d_in[2];
    const void* conv_w  = d_in[3];
    const void* conv_b  = d_in[4];
    const void* A_log   = d_in[5];
    const void* Dv      = d_in[6];
    const void* w_xproj = d_in[7];
    const void* w_dt    = d_in[8];
    const void* b_dt    = d_in[9];
    const void* w_out   = d_in[10];

    // disjoint workspace layout (~69 MB of the ~260 MB ws)
    char* ws = (char*)d_ws;
    const size_t MB = 1048576;
    unsigned short* xs_raw  = (unsigned short*)(ws);            // 8 MB
    unsigned short* res_s   = (unsigned short*)(ws + 8 * MB);   // 8 MB (inner in-place)
    unsigned short* xs_conv = (unsigned short*)(ws + 16 * MB);  // 8 MB
    unsigned short* delta   = (unsigned short*)(ws + 24 * MB);  // 8 MB
    unsigned short* h_norm  = (unsigned short*)(ws + 32 * MB);  // 4 MB
    unsigned short* wT      = (unsigned short*)(ws + 36 * MB);  // 8 MB
    unsigned short* woT     = (unsigned short*)(ws + 44 * MB);  // 4 MB
    float*          partials= (float*)(ws + 48 * MB);           // 8 MB
    float*          proj    = (float*)(ws + 56 * MB);           // 1 MB
    float*          Aprod   = (float*)(ws + 57 * MB);           // 4 MB (32 chunks)
    float*          Send    = (float*)(ws + 61 * MB);           // 4 MB
    float*          prefix  = (float*)(ws + 65 * MB);           // 4 MB
    unsigned short* inner   = res_s;                            // in-place (same-thread RAW)

    prep_kernel<<<3584, 256, 0, stream>>>(x, nscale, h_norm, w_in, wT, w_out, woT);
    gemm_bt_kernel<1024, 4096, 128, 0><<<dim3(64, 16), 256, 0, stream>>>(
        h_norm, wT, xs_raw, res_s, nullptr, nscale);
    conv_kernel<<<2048, 256, 0, stream>>>(xs_raw, conv_w, conv_b, xs_conv, nscale);
    xproj_gemm_kernel<<<dim3(2, 32, 8), 256, 0, stream>>>(xs_conv, w_xproj, partials, nscale);
    xproj_reduce_kernel<<<1024, 256, 0, stream>>>(partials, proj);
    delta_gemm_kernel<<<dim3(32, 32), 256, 0, stream>>>(proj, w_dt, b_dt, delta, nscale);
    scanA_kernel<<<dim3(32, 128), 256, 0, stream>>>(delta, xs_conv, proj, A_log, Aprod, Send, nscale);
    scanB_kernel<<<128, 256, 0, stream>>>(Aprod, Send, prefix);
    scanC_kernel<<<dim3(32, 128), 256, 0, stream>>>(delta, xs_conv, proj, A_log, Dv, prefix, res_s, inner, nscale);
    gemm_bt_kernel<2048, 1024, 64, 1><<<dim3(16, 32), 256, 0, stream>>>(
        inner, woT, d_out, nullptr, x, nscale);
}